// Round 1
// 110.888 us; speedup vs baseline: 1.1550x; 1.1550x over previous
//
#include <hip/hip_runtime.h>

#define BATCH 4
#define HH 56
#define WW 56
#define CC 128
#define NHD 4
#define HD 32
#define KS 7
#define NB 3
#define HWSZ (HH * WW)        // 3136
#define RPBW 13
#define QKV_N 384
#define QKV_ELE ((size_t)BATCH * NHD * HWSZ * HD)   // 1,605,632 floats per tensor

typedef unsigned short u16;
typedef unsigned int   u32;
typedef short bf16x8 __attribute__((ext_vector_type(8)));
typedef float f32x4  __attribute__((ext_vector_type(4)));

// RNE float -> bf16 (bit trick; data has no NaN/overflow concerns)
static __device__ __forceinline__ u32 f2bf(float f) {
    u32 u = __float_as_uint(f);
    return (u + 0x7FFFu + ((u >> 16) & 1u)) >> 16;
}
static __device__ __forceinline__ float bf2f(u32 h) { return __uint_as_float(h << 16); }

// ---------------- Kernel 0: weight prep (transpose + bf16 hi/lo split) ----
// w_qkv [128][384] -> wqT hi/lo [384][128]; w_proj [128][128] -> wpT hi/lo.
// One-time cost; makes GEMM B-staging a pure vector copy (no transpose).
__global__ __launch_bounds__(256) void prep_w(
    const float* __restrict__ w_qkv, const float* __restrict__ w_proj,
    u16* __restrict__ wqT_h, u16* __restrict__ wqT_l,
    u16* __restrict__ wpT_h, u16* __restrict__ wpT_l)
{
    const int e = blockIdx.x * 256 + threadIdx.x;   // 0..65535 exact
    float v; u16 *dh, *dl; int idx;
    if (e < 384 * 128) {
        const int n = e >> 7, k = e & 127;
        v = w_qkv[k * QKV_N + n];
        dh = wqT_h; dl = wqT_l; idx = e;
    } else {
        const int e2 = e - 384 * 128;
        const int n = e2 >> 7, k = e2 & 127;
        v = w_proj[k * CC + n];
        dh = wpT_h; dl = wpT_l; idx = e2;
    }
    const u32 h = f2bf(v);
    dh[idx] = (u16)h;
    dl[idx] = (u16)f2bf(v - bf2f(h));
}

#define LP 72   // LDS row pitch in ushorts (144 B = 9*16 B: aligned + bank-balanced)

// ---------------- Kernel 1: QKV GEMM via split-bf16 MFMA ----------------
// x[12544,128] @ w[128,384]. BM=64, BN=128 (one tensor), K-chunk 64.
// 4 waves 2x2: each wave 32 rows x 64 cols = 8 16x16 tiles.
// acc = Ah*Bh + Ah*Bl + Al*Bh  (fp32-equivalent precision, rel err ~2^-18).
__global__ __launch_bounds__(256) void qkv_mfma(
    const float* __restrict__ x, const u16* __restrict__ wT_h,
    const u16* __restrict__ wT_l, const float* __restrict__ bias,
    float* __restrict__ qb, float* __restrict__ kb, float* __restrict__ vb)
{
    __shared__ __align__(16) u16 Ah[64 * LP], Al[64 * LP];
    __shared__ __align__(16) u16 Bh[128 * LP], Bl[128 * LP];

    const int tid  = threadIdx.x;
    const int lane = tid & 63;
    const int w    = tid >> 6;
    const int wr = w >> 1, wc = w & 1;
    const int lr = lane >> 4, lc = lane & 15;
    const int m0 = blockIdx.x * 64;
    const int tz = blockIdx.y;            // 0=q 1=k 2=v

    f32x4 acc[2][4];
    #pragma unroll
    for (int nt = 0; nt < 4; ++nt) {      // init with bias (uniform over rows)
        const float bn = bias[tz * 128 + wc * 64 + nt * 16 + lc];
        acc[0][nt] = (f32x4){bn, bn, bn, bn};
        acc[1][nt] = acc[0][nt];
    }

    for (int kc = 0; kc < 128; kc += 64) {
        // stage A: 64 rows x 64 k fp32 -> hi/lo bf16 (cvt in registers)
        #pragma unroll
        for (int it = 0; it < 4; ++it) {
            const int task = tid + it * 256;          // 0..1023
            const int row = task >> 4, q4 = task & 15;
            const float4 xv = *(const float4*)(x + (size_t)(m0 + row) * CC + kc + 4 * q4);
            const u32 h0 = f2bf(xv.x), h1 = f2bf(xv.y), h2 = f2bf(xv.z), h3 = f2bf(xv.w);
            const u32 l0 = f2bf(xv.x - bf2f(h0)), l1 = f2bf(xv.y - bf2f(h1));
            const u32 l2 = f2bf(xv.z - bf2f(h2)), l3 = f2bf(xv.w - bf2f(h3));
            const int off = row * LP + 4 * q4;
            *(uint2*)&Ah[off] = make_uint2(h0 | (h1 << 16), h2 | (h3 << 16));
            *(uint2*)&Al[off] = make_uint2(l0 | (l1 << 16), l2 | (l3 << 16));
        }
        // stage B: 128 n x 64 k, straight copy from pre-split wT [n][128]
        #pragma unroll
        for (int it = 0; it < 8; ++it) {
            const int task = tid + it * 256;          // 0..2047 (it<4: hi, it>=4: lo)
            const int hl = task >> 10;
            const int t2 = task & 1023;
            const int n = t2 >> 3, q8 = t2 & 7;
            const u16* src = (hl ? wT_l : wT_h) + (size_t)(tz * 128 + n) * CC + kc + 8 * q8;
            const uint4 vv = *(const uint4*)src;
            u16* dst = (hl ? Bl : Bh) + n * LP + 8 * q8;
            *(uint4*)dst = vv;
        }
        __syncthreads();
        #pragma unroll
        for (int s = 0; s < 2; ++s) {                 // two K=32 steps per chunk
            const int ko = 32 * s + 8 * lr;
            bf16x8 bfh[4], bfl[4];
            #pragma unroll
            for (int nt = 0; nt < 4; ++nt) {
                const int bo = (wc * 64 + nt * 16 + lc) * LP + ko;
                bfh[nt] = *(const bf16x8*)&Bh[bo];
                bfl[nt] = *(const bf16x8*)&Bl[bo];
            }
            #pragma unroll
            for (int mt = 0; mt < 2; ++mt) {
                const int ao = (wr * 32 + mt * 16 + lc) * LP + ko;
                const bf16x8 afh = *(const bf16x8*)&Ah[ao];
                const bf16x8 afl = *(const bf16x8*)&Al[ao];
                #pragma unroll
                for (int nt = 0; nt < 4; ++nt) {
                    acc[mt][nt] = __builtin_amdgcn_mfma_f32_16x16x32_bf16(afh, bfh[nt], acc[mt][nt], 0, 0, 0);
                    acc[mt][nt] = __builtin_amdgcn_mfma_f32_16x16x32_bf16(afh, bfl[nt], acc[mt][nt], 0, 0, 0);
                    acc[mt][nt] = __builtin_amdgcn_mfma_f32_16x16x32_bf16(afl, bfh[nt], acc[mt][nt], 0, 0, 0);
                }
            }
        }
        __syncthreads();
    }

    // scatter into q/k/v [B,NH,HW,HD]; C/D layout: col=lane&15, row=(lane>>4)*4+r
    float* dst      = (tz == 0) ? qb : (tz == 1) ? kb : vb;
    const float scl = (tz == 0) ? 0.17677669529663687f : 1.0f;
    const int b = m0 / HWSZ;              // 64 | 3136 so tile never crosses b
    #pragma unroll
    for (int mt = 0; mt < 2; ++mt) {
        #pragma unroll
        for (int nt = 0; nt < 4; ++nt) {
            const int n = wc * 64 + nt * 16 + lc;
            const int head = n >> 5, d = n & 31;
            #pragma unroll
            for (int r = 0; r < 4; ++r) {
                const int m  = m0 + wr * 32 + mt * 16 + lr * 4 + r;
                const int ij = m - b * HWSZ;
                dst[((size_t)(b * NHD + head) * HWSZ + ij) * HD + d] = acc[mt][nt][r] * scl;
            }
        }
    }
}

// ---------------- Kernel 2: neighborhood attention (unchanged) ----------------
__global__ __launch_bounds__(256) void natten_attn(
    const float* __restrict__ qb, const float* __restrict__ kb,
    const float* __restrict__ vb, const float* __restrict__ rpb,
    float* __restrict__ ob)
{
    __shared__ float4 Ks[8][197];   // [c][pos]
    __shared__ float4 Vs[8][197];
    __shared__ float rpbs[RPBW * RPBW];

    const int tid = threadIdx.x;
    const int qid = tid >> 2;       // 0..63 query within 8x8 tile
    const int sub = tid & 3;        // channel-quarter
    const int qi_l = qid >> 3;
    const int qj_l = qid & 7;
    const int ti = blockIdx.x / 7;
    const int tj = blockIdx.x % 7;
    const int head = blockIdx.y;
    const int b    = blockIdx.z;
    const int qi = ti * 8 + qi_l;
    const int qj = tj * 8 + qj_l;
    const int R0 = min(max(ti * 8 - NB, 0), HH - 14);
    const int C0 = min(max(tj * 8 - NB, 0), WW - 14);

    const size_t base = (size_t)(b * NHD + head) * HWSZ;

    if (tid < RPBW * RPBW) rpbs[tid] = rpb[head * (RPBW * RPBW) + tid];

    for (int idx = tid; idx < 1568; idx += 256) {
        const int pos = idx >> 3;
        const int c   = idx & 7;
        const int ri  = pos / 14;
        const int rj  = pos - ri * 14;
        const size_t g = (base + (size_t)(R0 + ri) * WW + (C0 + rj)) * HD;
        Ks[c][pos] = ((const float4*)(kb + g))[c];
        Vs[c][pos] = ((const float4*)(vb + g))[c];
    }

    const int c0 = sub * 2;
    const float4* qp = (const float4*)(qb + (base + (size_t)qi * WW + qj) * HD) + c0;
    const float4 q0 = qp[0];
    const float4 q1 = qp[1];

    const int si  = min(max(qi - NB, 0), HH - KS);
    const int sj  = min(max(qj - NB, 0), WW - KS);
    const int ri0 = si - R0;
    const int rj0 = sj - C0;
    const int oi  = si - qi + (KS - 1);
    const int oj  = sj - qj + (KS - 1);

    __syncthreads();

    float s[49];
    #pragma unroll
    for (int pi = 0; pi < 7; ++pi) {
        const int rowoff = (ri0 + pi) * 14 + rj0;
        const int boff   = (oi + pi) * RPBW + oj;
        #pragma unroll
        for (int pj = 0; pj < 7; ++pj) {
            const int pos = rowoff + pj;
            const float4 k0 = Ks[c0][pos];
            const float4 k1 = Ks[c0 + 1][pos];
            float d = q0.x * k0.x + q0.y * k0.y + q0.z * k0.z + q0.w * k0.w
                    + q1.x * k1.x + q1.y * k1.y + q1.z * k1.z + q1.w * k1.w;
            d += __shfl_xor(d, 1, 64);
            d += __shfl_xor(d, 2, 64);
            s[pi * 7 + pj] = d + rpbs[boff + pj];
        }
    }

    float m = s[0];
    #pragma unroll
    for (int p = 1; p < 49; ++p) m = fmaxf(m, s[p]);
    float l = 0.f;
    #pragma unroll
    for (int p = 0; p < 49; ++p) { s[p] = __expf(s[p] - m); l += s[p]; }
    const float inv = 1.f / l;

    float4 o0 = make_float4(0.f, 0.f, 0.f, 0.f);
    float4 o1 = make_float4(0.f, 0.f, 0.f, 0.f);
    #pragma unroll
    for (int pi = 0; pi < 7; ++pi) {
        const int rowoff = (ri0 + pi) * 14 + rj0;
        #pragma unroll
        for (int pj = 0; pj < 7; ++pj) {
            const int pos = rowoff + pj;
            const float wt = s[pi * 7 + pj];
            const float4 v0 = Vs[c0][pos];
            const float4 v1 = Vs[c0 + 1][pos];
            o0.x += wt * v0.x; o0.y += wt * v0.y; o0.z += wt * v0.z; o0.w += wt * v0.w;
            o1.x += wt * v1.x; o1.y += wt * v1.y; o1.z += wt * v1.z; o1.w += wt * v1.w;
        }
    }

    float* op = ob + ((size_t)b * HWSZ + (size_t)qi * WW + qj) * CC + head * HD + sub * 8;
    ((float4*)op)[0] = make_float4(o0.x * inv, o0.y * inv, o0.z * inv, o0.w * inv);
    ((float4*)op)[1] = make_float4(o1.x * inv, o1.y * inv, o1.z * inv, o1.w * inv);
}

// ---------------- Kernel 3: output projection via split-bf16 MFMA --------
// a[12544,128] @ w_proj[128,128]. BM=32, BN=128, grid 392. 4 waves 2x2:
// each wave 16 rows x 64 cols = 4 16x16 tiles.
__global__ __launch_bounds__(256) void proj_mfma(
    const float* __restrict__ a, const u16* __restrict__ wT_h,
    const u16* __restrict__ wT_l, const float* __restrict__ bias,
    float* __restrict__ out)
{
    __shared__ __align__(16) u16 Ah[32 * LP], Al[32 * LP];
    __shared__ __align__(16) u16 Bh[128 * LP], Bl[128 * LP];

    const int tid  = threadIdx.x;
    const int lane = tid & 63;
    const int w    = tid >> 6;
    const int wr = w >> 1, wc = w & 1;
    const int lr = lane >> 4, lc = lane & 15;
    const int m0 = blockIdx.x * 32;

    f32x4 acc[4];
    #pragma unroll
    for (int nt = 0; nt < 4; ++nt) {
        const float bn = bias[wc * 64 + nt * 16 + lc];
        acc[nt] = (f32x4){bn, bn, bn, bn};
    }

    for (int kc = 0; kc < 128; kc += 64) {
        #pragma unroll
        for (int it = 0; it < 2; ++it) {
            const int task = tid + it * 256;          // 0..511
            const int row = task >> 4, q4 = task & 15;
            const float4 xv = *(const float4*)(a + (size_t)(m0 + row) * CC + kc + 4 * q4);
            const u32 h0 = f2bf(xv.x), h1 = f2bf(xv.y), h2 = f2bf(xv.z), h3 = f2bf(xv.w);
            const u32 l0 = f2bf(xv.x - bf2f(h0)), l1 = f2bf(xv.y - bf2f(h1));
            const u32 l2 = f2bf(xv.z - bf2f(h2)), l3 = f2bf(xv.w - bf2f(h3));
            const int off = row * LP + 4 * q4;
            *(uint2*)&Ah[off] = make_uint2(h0 | (h1 << 16), h2 | (h3 << 16));
            *(uint2*)&Al[off] = make_uint2(l0 | (l1 << 16), l2 | (l3 << 16));
        }
        #pragma unroll
        for (int it = 0; it < 8; ++it) {
            const int task = tid + it * 256;          // 0..2047
            const int hl = task >> 10;
            const int t2 = task & 1023;
            const int n = t2 >> 3, q8 = t2 & 7;
            const u16* src = (hl ? wT_l : wT_h) + (size_t)n * CC + kc + 8 * q8;
            const uint4 vv = *(const uint4*)src;
            u16* dst = (hl ? Bl : Bh) + n * LP + 8 * q8;
            *(uint4*)dst = vv;
        }
        __syncthreads();
        #pragma unroll
        for (int s = 0; s < 2; ++s) {
            const int ko = 32 * s + 8 * lr;
            const int ao = (wr * 16 + lc) * LP + ko;
            const bf16x8 afh = *(const bf16x8*)&Ah[ao];
            const bf16x8 afl = *(const bf16x8*)&Al[ao];
            #pragma unroll
            for (int nt = 0; nt < 4; ++nt) {
                const int bo = (wc * 64 + nt * 16 + lc) * LP + ko;
                const bf16x8 bh = *(const bf16x8*)&Bh[bo];
                const bf16x8 bl = *(const bf16x8*)&Bl[bo];
                acc[nt] = __builtin_amdgcn_mfma_f32_16x16x32_bf16(afh, bh, acc[nt], 0, 0, 0);
                acc[nt] = __builtin_amdgcn_mfma_f32_16x16x32_bf16(afh, bl, acc[nt], 0, 0, 0);
                acc[nt] = __builtin_amdgcn_mfma_f32_16x16x32_bf16(afl, bh, acc[nt], 0, 0, 0);
            }
        }
        __syncthreads();
    }

    #pragma unroll
    for (int nt = 0; nt < 4; ++nt) {
        const int n = wc * 64 + nt * 16 + lc;
        #pragma unroll
        for (int r = 0; r < 4; ++r) {
            const int m = m0 + wr * 16 + lr * 4 + r;
            out[(size_t)m * CC + n] = acc[nt][r];
        }
    }
}

extern "C" void kernel_launch(void* const* d_in, const int* in_sizes, int n_in,
                              void* d_out, int out_size, void* d_ws, size_t ws_size,
                              hipStream_t stream) {
    const float* x      = (const float*)d_in[0];
    const float* w_qkv  = (const float*)d_in[1];
    const float* b_qkv  = (const float*)d_in[2];
    const float* rpb    = (const float*)d_in[3];
    const float* w_proj = (const float*)d_in[4];
    const float* b_proj = (const float*)d_in[5];
    float* out = (float*)d_out;

    float* ws  = (float*)d_ws;
    float* qbf = ws;
    float* kbf = ws + QKV_ELE;
    float* vbf = ws + 2 * QKV_ELE;
    float* obf = ws + 3 * QKV_ELE;
    u16* wqT_h = (u16*)(ws + 4 * QKV_ELE);
    u16* wqT_l = wqT_h + 384 * 128;
    u16* wpT_h = wqT_l + 384 * 128;
    u16* wpT_l = wpT_h + 128 * 128;

    prep_w<<<256, 256, 0, stream>>>(w_qkv, w_proj, wqT_h, wqT_l, wpT_h, wpT_l);
    qkv_mfma<<<dim3(196, 3), 256, 0, stream>>>(x, wqT_h, wqT_l, b_qkv, qbf, kbf, vbf);
    natten_attn<<<dim3(49, NHD, BATCH), 256, 0, stream>>>(qbf, kbf, vbf, rpb, obf);
    proj_mfma<<<392, 256, 0, stream>>>(obf, wpT_h, wpT_l, b_proj, out);
}

// Round 2
// 108.781 us; speedup vs baseline: 1.1774x; 1.0194x over previous
//
#include <hip/hip_runtime.h>

#define BATCH 4
#define HH 56
#define WW 56
#define CC 128
#define NHD 4
#define HD 32
#define KS 7
#define NB 3
#define HWSZ (HH * WW)        // 3136
#define RPBW 13
#define QKV_N 384
#define QKV_ELE ((size_t)BATCH * NHD * HWSZ * HD)   // 1,605,632 floats per tensor

typedef unsigned short u16;
typedef unsigned int   u32;
typedef short bf16x8 __attribute__((ext_vector_type(8)));
typedef short bf16x4 __attribute__((ext_vector_type(4)));
typedef float f32x4  __attribute__((ext_vector_type(4)));

// RNE float -> bf16 (bit trick; data has no NaN/overflow concerns)
static __device__ __forceinline__ u32 f2bf(float f) {
    u32 u = __float_as_uint(f);
    return (u + 0x7FFFu + ((u >> 16) & 1u)) >> 16;
}
static __device__ __forceinline__ float bf2f(u32 h) { return __uint_as_float(h << 16); }

// packed f32x2 -> bf16x2 (RNE), lo in [15:0], hi in [31:16]
static __device__ __forceinline__ u32 cvtpk(float lo, float hi) {
    u32 d;
    asm("v_cvt_pk_bf16_f32 %0, %1, %2" : "=v"(d) : "v"(lo), "v"(hi));
    return d;
}
// split (a,b) into packed bf16 hi-word + packed bf16 residual word
static __device__ __forceinline__ void split2(float a, float b, u32& h, u32& l) {
    h = cvtpk(a, b);
    l = cvtpk(a - __uint_as_float(h << 16), b - __uint_as_float(h & 0xffff0000u));
}

#if __has_builtin(__builtin_amdgcn_mfma_f32_16x16x16bf16_1k)
#define MFMA16(a, b, c) __builtin_amdgcn_mfma_f32_16x16x16bf16_1k(a, b, c, 0, 0, 0)
#else
static __device__ __forceinline__ f32x4 mfma16_asm(bf16x4 a, bf16x4 b, f32x4 c) {
    asm("v_mfma_f32_16x16x16_bf16 %0, %1, %2, %0" : "+v"(c) : "v"(a), "v"(b));
    return c;
}
#define MFMA16(a, b, c) mfma16_asm(a, b, c)
#endif

// ---------------- Kernel 0: weight prep (transpose + bf16 hi/lo split) ----
__global__ __launch_bounds__(256) void prep_w(
    const float* __restrict__ w_qkv, const float* __restrict__ w_proj,
    u16* __restrict__ wqT_h, u16* __restrict__ wqT_l,
    u16* __restrict__ wpT_h, u16* __restrict__ wpT_l)
{
    const int e = blockIdx.x * 256 + threadIdx.x;   // 0..65535 exact
    float v; u16 *dh, *dl; int idx;
    if (e < 384 * 128) {
        const int n = e >> 7, k = e & 127;
        v = w_qkv[k * QKV_N + n];
        dh = wqT_h; dl = wqT_l; idx = e;
    } else {
        const int e2 = e - 384 * 128;
        const int n = e2 >> 7, k = e2 & 127;
        v = w_proj[k * CC + n];
        dh = wpT_h; dl = wpT_l; idx = e2;
    }
    const u32 h = f2bf(v);
    dh[idx] = (u16)h;
    dl[idx] = (u16)f2bf(v - bf2f(h));
}

#define LP 72   // GEMM LDS row pitch in ushorts (144 B = 9*16 B)

// ---------------- Kernel 1: QKV GEMM via split-bf16 MFMA ----------------
__global__ __launch_bounds__(256) void qkv_mfma(
    const float* __restrict__ x, const u16* __restrict__ wT_h,
    const u16* __restrict__ wT_l, const float* __restrict__ bias,
    float* __restrict__ qb, float* __restrict__ kb, float* __restrict__ vb)
{
    __shared__ __align__(16) u16 Ah[64 * LP], Al[64 * LP];
    __shared__ __align__(16) u16 Bh[128 * LP], Bl[128 * LP];

    const int tid  = threadIdx.x;
    const int lane = tid & 63;
    const int w    = tid >> 6;
    const int wr = w >> 1, wc = w & 1;
    const int lr = lane >> 4, lc = lane & 15;
    const int m0 = blockIdx.x * 64;
    const int tz = blockIdx.y;            // 0=q 1=k 2=v

    f32x4 acc[2][4];
    #pragma unroll
    for (int nt = 0; nt < 4; ++nt) {
        const float bn = bias[tz * 128 + wc * 64 + nt * 16 + lc];
        acc[0][nt] = (f32x4){bn, bn, bn, bn};
        acc[1][nt] = acc[0][nt];
    }

    for (int kc = 0; kc < 128; kc += 64) {
        #pragma unroll
        for (int it = 0; it < 4; ++it) {
            const int task = tid + it * 256;
            const int row = task >> 4, q4 = task & 15;
            const float4 xv = *(const float4*)(x + (size_t)(m0 + row) * CC + kc + 4 * q4);
            u32 h0, l0, h1, l1;
            split2(xv.x, xv.y, h0, l0);
            split2(xv.z, xv.w, h1, l1);
            const int off = row * LP + 4 * q4;
            *(uint2*)&Ah[off] = make_uint2(h0, h1);
            *(uint2*)&Al[off] = make_uint2(l0, l1);
        }
        #pragma unroll
        for (int it = 0; it < 8; ++it) {
            const int task = tid + it * 256;
            const int hl = task >> 10;
            const int t2 = task & 1023;
            const int n = t2 >> 3, q8 = t2 & 7;
            const u16* src = (hl ? wT_l : wT_h) + (size_t)(tz * 128 + n) * CC + kc + 8 * q8;
            const uint4 vv = *(const uint4*)src;
            u16* dst = (hl ? Bl : Bh) + n * LP + 8 * q8;
            *(uint4*)dst = vv;
        }
        __syncthreads();
        #pragma unroll
        for (int s = 0; s < 2; ++s) {
            const int ko = 32 * s + 8 * lr;
            bf16x8 bfh[4], bfl[4];
            #pragma unroll
            for (int nt = 0; nt < 4; ++nt) {
                const int bo = (wc * 64 + nt * 16 + lc) * LP + ko;
                bfh[nt] = *(const bf16x8*)&Bh[bo];
                bfl[nt] = *(const bf16x8*)&Bl[bo];
            }
            #pragma unroll
            for (int mt = 0; mt < 2; ++mt) {
                const int ao = (wr * 32 + mt * 16 + lc) * LP + ko;
                const bf16x8 afh = *(const bf16x8*)&Ah[ao];
                const bf16x8 afl = *(const bf16x8*)&Al[ao];
                #pragma unroll
                for (int nt = 0; nt < 4; ++nt) {
                    acc[mt][nt] = __builtin_amdgcn_mfma_f32_16x16x32_bf16(afh, bfh[nt], acc[mt][nt], 0, 0, 0);
                    acc[mt][nt] = __builtin_amdgcn_mfma_f32_16x16x32_bf16(afh, bfl[nt], acc[mt][nt], 0, 0, 0);
                    acc[mt][nt] = __builtin_amdgcn_mfma_f32_16x16x32_bf16(afl, bfh[nt], acc[mt][nt], 0, 0, 0);
                }
            }
        }
        __syncthreads();
    }

    const int tzz = tz;
    float* dst      = (tzz == 0) ? qb : (tzz == 1) ? kb : vb;
    const float scl = (tzz == 0) ? 0.17677669529663687f : 1.0f;
    const int b = m0 / HWSZ;
    #pragma unroll
    for (int mt = 0; mt < 2; ++mt) {
        #pragma unroll
        for (int nt = 0; nt < 4; ++nt) {
            const int n = wc * 64 + nt * 16 + lc;
            const int head = n >> 5, d = n & 31;
            #pragma unroll
            for (int r = 0; r < 4; ++r) {
                const int m  = m0 + wr * 32 + mt * 16 + lr * 4 + r;
                const int ij = m - b * HWSZ;
                dst[((size_t)(b * NHD + head) * HWSZ + ij) * HD + d] = acc[mt][nt][r] * scl;
            }
        }
    }
}

// ---------------- Kernel 2: neighborhood attention via MFMA ----------------
// Block = (b, head, 8x8 query tile), 256 thr = 4 waves, each wave owns 16
// queries (2 rows). S^T = K·Q^T (swapped: softmax is lane-local), masked
// bias over the 14x14 halo; each wave touches only its 8-key-tile band.
// PV uses 16x16x16 MFMA: A-operand k-layout == C-frag row layout, so P
// feeds from QK accumulators with no cross-lane traffic.
__global__ __launch_bounds__(256) void natten_attn(
    const float* __restrict__ qb, const float* __restrict__ kb,
    const float* __restrict__ vb, const float* __restrict__ rpb,
    float* __restrict__ ob)
{
    __shared__ __align__(16) u16 KhS[208 * 32];       // [pos][d] bf16 hi
    __shared__ __align__(16) u16 KlS[208 * 32];       // residual
    __shared__ __align__(16) u16 VhS[26 * 16 * 20];   // [nt*13+t][c][kk] pitch 20
    __shared__ __align__(16) u16 VlS[26 * 16 * 20];
    __shared__ float rpbs[RPBW * RPBW];

    const int tid  = threadIdx.x;
    const int lane = tid & 63;
    const int wv   = tid >> 6;      // wave id 0..3
    const int g    = lane >> 4;     // 16-lane group
    const int cl   = lane & 15;

    const int ti = blockIdx.x / 7;
    const int tj = blockIdx.x % 7;
    const int head = blockIdx.y;
    const int b    = blockIdx.z;
    const int R0 = min(max(ti * 8 - NB, 0), HH - 14);
    const int C0 = min(max(tj * 8 - NB, 0), WW - 14);
    const size_t base = (size_t)(b * NHD + head) * HWSZ;

    // ---- Q fragment direct from global: query 16*wv+cl, d = 8g..8g+7
    const int qlq = 16 * wv + cl;
    const int qi  = ti * 8 + (qlq >> 3);
    const int qj  = tj * 8 + (qlq & 7);
    const float* qp = qb + (base + (size_t)qi * WW + qj) * HD + 8 * g;
    const float4 qv0 = *(const float4*)qp;
    const float4 qv1 = *(const float4*)(qp + 4);

    union U8 { u32 u[4]; bf16x8 v; };
    U8 uqh, uql;
    split2(qv0.x, qv0.y, uqh.u[0], uql.u[0]);
    split2(qv0.z, qv0.w, uqh.u[1], uql.u[1]);
    split2(qv1.x, qv1.y, uqh.u[2], uql.u[2]);
    split2(qv1.z, qv1.w, uqh.u[3], uql.u[3]);
    const bf16x8 Qh = uqh.v;
    const bf16x8 Ql = uql.v;

    if (tid < RPBW * RPBW) rpbs[tid] = rpb[head * (RPBW * RPBW) + tid];

    // ---- stage K (196 pos x 32 d, bf16 hi/lo)
    for (int idx = tid; idx < 1568; idx += 256) {
        const int pos = idx >> 3, c4 = idx & 7;
        const int ri = (pos * 293) >> 12;       // pos / 14 (exact for pos<683)
        const int rj = pos - ri * 14;
        const float4 kv = *(const float4*)(kb + (base + (size_t)(R0 + ri) * WW + (C0 + rj)) * HD + 4 * c4);
        u32 h0, l0, h1, l1;
        split2(kv.x, kv.y, h0, l0);
        split2(kv.z, kv.w, h1, l1);
        *(uint2*)&KhS[pos * 32 + 4 * c4] = make_uint2(h0, h1);
        *(uint2*)&KlS[pos * 32 + 4 * c4] = make_uint2(l0, l1);
    }
    // ---- stage V transposed to [nt][t][c][kk] (pairs of pos -> one u32)
    for (int idx = tid; idx < 784; idx += 256) {
        const int pr = idx >> 3, c4 = idx & 7;
        const int pos0 = 2 * pr;
        const int ri0 = (pos0 * 293) >> 12;       const int rj0 = pos0 - ri0 * 14;
        const int ri1 = ((pos0 + 1) * 293) >> 12; const int rj1 = pos0 + 1 - ri1 * 14;
        const float4 va = *(const float4*)(vb + (base + (size_t)(R0 + ri0) * WW + (C0 + rj0)) * HD + 4 * c4);
        const float4 vc = *(const float4*)(vb + (base + (size_t)(R0 + ri1) * WW + (C0 + rj1)) * HD + 4 * c4);
        const int t = pos0 >> 4, kk = pos0 & 15;
        const float a0[4] = {va.x, va.y, va.z, va.w};
        const float a1[4] = {vc.x, vc.y, vc.z, vc.w};
        #pragma unroll
        for (int i = 0; i < 4; ++i) {
            const int d = 4 * c4 + i;
            const int nt = d >> 4, cd = d & 15;
            u32 hh, ll;
            split2(a0[i], a1[i], hh, ll);
            const int off = ((nt * 13 + t) * 16 + cd) * 20 + kk;
            *(u32*)&VhS[off] = hh;
            *(u32*)&VlS[off] = ll;
        }
    }
    // zero-pad V for pos 196..207 (t=12, kk>=4) so P=0 * garbage never NaNs
    for (int idx = tid; idx < 384; idx += 256) {
        const int kp = idx % 6;
        int r = idx / 6;
        const int cd = r & 15; r >>= 4;
        const int nt = r & 1;  const int arr = r >> 1;
        u16* dst = arr ? VlS : VhS;
        *(u32*)&dst[((nt * 13 + 12) * 16 + cd) * 20 + 4 + 2 * kp] = 0u;
    }
    __syncthreads();

    // ---- per-wave key-tile band: 2 query rows touch <= 8 halo rows = 8 tiles
    const int qi0  = ti * 8 + 2 * wv;
    const int s_lo = min(max(qi0 - NB, 0), HH - KS);
    const int t0   = min(((s_lo - R0) * 14) >> 4, 5);

    // ---- S^T = K·Q^T  (3-term split-bf16), keys 16*(t0+tt)+4g+r, query 16wv+cl
    f32x4 p[8];
    #pragma unroll
    for (int tt = 0; tt < 8; ++tt) p[tt] = (f32x4){0.f, 0.f, 0.f, 0.f};
    #pragma unroll
    for (int tt = 0; tt < 8; ++tt) {
        const int ro = (16 * (t0 + tt) + cl) * 32 + 8 * g;
        const bf16x8 kh = *(const bf16x8*)&KhS[ro];
        const bf16x8 kl = *(const bf16x8*)&KlS[ro];
        p[tt] = __builtin_amdgcn_mfma_f32_16x16x32_bf16(kh, Qh, p[tt], 0, 0, 0);
        p[tt] = __builtin_amdgcn_mfma_f32_16x16x32_bf16(kh, Ql, p[tt], 0, 0, 0);
        p[tt] = __builtin_amdgcn_mfma_f32_16x16x32_bf16(kl, Qh, p[tt], 0, 0, 0);
    }

    // ---- mask + rpb bias, lane-local softmax (one query per lane-column)
    const int si = min(max(qi - NB, 0), HH - KS);
    const int sj = min(max(qj - NB, 0), WW - KS);
    const int r_si = si - R0, c_sj = sj - C0;
    const int aq = qi - R0, bq = qj - C0;

    float mmax = -3.0e38f;
    #pragma unroll
    for (int tt = 0; tt < 8; ++tt) {
        #pragma unroll
        for (int r = 0; r < 4; ++r) {
            const int pp = 16 * (t0 + tt) + 4 * g + r;
            const int rowp = (pp * 293) >> 12;
            const int colp = pp - rowp * 14;
            const bool ok = (pp < 196) && ((u32)(rowp - r_si) <= 6u) && ((u32)(colp - c_sj) <= 6u);
            int bidx = (rowp - aq + 6) * RPBW + (colp - bq + 6);
            bidx = ok ? bidx : 0;
            const float sv = ok ? (p[tt][r] + rpbs[bidx]) : -3.0e38f;
            p[tt][r] = sv;
            mmax = fmaxf(mmax, sv);
        }
    }
    mmax = fmaxf(mmax, __shfl_xor(mmax, 16, 64));
    mmax = fmaxf(mmax, __shfl_xor(mmax, 32, 64));

    float lsum = 0.f;
    #pragma unroll
    for (int tt = 0; tt < 8; ++tt) {
        #pragma unroll
        for (int r = 0; r < 4; ++r) {
            const float e = __expf(p[tt][r] - mmax);
            p[tt][r] = e;
            lsum += e;
        }
    }
    lsum += __shfl_xor(lsum, 16, 64);
    lsum += __shfl_xor(lsum, 32, 64);
    const float inv = 1.f / lsum;

    // ---- P -> bf16 hi/lo A-fragments (zero cross-lane movement)
    bf16x4 pah[8], pal[8];
    #pragma unroll
    for (int tt = 0; tt < 8; ++tt) {
        const float p0 = p[tt][0] * inv, p1 = p[tt][1] * inv;
        const float p2 = p[tt][2] * inv, p3 = p[tt][3] * inv;
        union U4 { u32 u[2]; bf16x4 v; } ua, ub;
        split2(p0, p1, ua.u[0], ub.u[0]);
        split2(p2, p3, ua.u[1], ub.u[1]);
        pah[tt] = ua.v;
        pal[tt] = ub.v;
    }

    // ---- O = P·V  (16x16x16, 3-term split)
    f32x4 o[2];
    o[0] = (f32x4){0.f, 0.f, 0.f, 0.f};
    o[1] = (f32x4){0.f, 0.f, 0.f, 0.f};
    #pragma unroll
    for (int tt = 0; tt < 8; ++tt) {
        const int t = t0 + tt;
        #pragma unroll
        for (int nt = 0; nt < 2; ++nt) {
            const int off = ((nt * 13 + t) * 16 + cl) * 20 + 4 * g;
            const bf16x4 vh = *(const bf16x4*)&VhS[off];
            const bf16x4 vl = *(const bf16x4*)&VlS[off];
            o[nt] = MFMA16(pah[tt], vh, o[nt]);
            o[nt] = MFMA16(pal[tt], vh, o[nt]);
            o[nt] = MFMA16(pah[tt], vl, o[nt]);
        }
    }

    // ---- write O: lane holds O[q=16wv+4g+r][d=16nt+cl]
    #pragma unroll
    for (int nt = 0; nt < 2; ++nt) {
        #pragma unroll
        for (int r = 0; r < 4; ++r) {
            const int qlo = 16 * wv + 4 * g + r;
            const int oqi = ti * 8 + (qlo >> 3);
            const int oqj = tj * 8 + (qlo & 7);
            ob[((size_t)b * HWSZ + (size_t)oqi * WW + oqj) * CC + head * HD + 16 * nt + cl] = o[nt][r];
        }
    }
}

// ---------------- Kernel 3: output projection via split-bf16 MFMA --------
__global__ __launch_bounds__(256) void proj_mfma(
    const float* __restrict__ a, const u16* __restrict__ wT_h,
    const u16* __restrict__ wT_l, const float* __restrict__ bias,
    float* __restrict__ out)
{
    __shared__ __align__(16) u16 Ah[32 * LP], Al[32 * LP];
    __shared__ __align__(16) u16 Bh[128 * LP], Bl[128 * LP];

    const int tid  = threadIdx.x;
    const int lane = tid & 63;
    const int w    = tid >> 6;
    const int wr = w >> 1, wc = w & 1;
    const int lr = lane >> 4, lc = lane & 15;
    const int m0 = blockIdx.x * 32;

    f32x4 acc[4];
    #pragma unroll
    for (int nt = 0; nt < 4; ++nt) {
        const float bn = bias[wc * 64 + nt * 16 + lc];
        acc[nt] = (f32x4){bn, bn, bn, bn};
    }

    for (int kc = 0; kc < 128; kc += 64) {
        #pragma unroll
        for (int it = 0; it < 2; ++it) {
            const int task = tid + it * 256;
            const int row = task >> 4, q4 = task & 15;
            const float4 xv = *(const float4*)(a + (size_t)(m0 + row) * CC + kc + 4 * q4);
            u32 h0, l0, h1, l1;
            split2(xv.x, xv.y, h0, l0);
            split2(xv.z, xv.w, h1, l1);
            const int off = row * LP + 4 * q4;
            *(uint2*)&Ah[off] = make_uint2(h0, h1);
            *(uint2*)&Al[off] = make_uint2(l0, l1);
        }
        #pragma unroll
        for (int it = 0; it < 8; ++it) {
            const int task = tid + it * 256;
            const int hl = task >> 10;
            const int t2 = task & 1023;
            const int n = t2 >> 3, q8 = t2 & 7;
            const u16* src = (hl ? wT_l : wT_h) + (size_t)n * CC + kc + 8 * q8;
            const uint4 vv = *(const uint4*)src;
            u16* dst = (hl ? Bl : Bh) + n * LP + 8 * q8;
            *(uint4*)dst = vv;
        }
        __syncthreads();
        #pragma unroll
        for (int s = 0; s < 2; ++s) {
            const int ko = 32 * s + 8 * lr;
            const int ao = (wr * 16 + lc) * LP + ko;
            const bf16x8 afh = *(const bf16x8*)&Ah[ao];
            const bf16x8 afl = *(const bf16x8*)&Al[ao];
            #pragma unroll
            for (int nt = 0; nt < 4; ++nt) {
                const int bo = (wc * 64 + nt * 16 + lc) * LP + ko;
                const bf16x8 bh = *(const bf16x8*)&Bh[bo];
                const bf16x8 bl = *(const bf16x8*)&Bl[bo];
                acc[nt] = __builtin_amdgcn_mfma_f32_16x16x32_bf16(afh, bh, acc[nt], 0, 0, 0);
                acc[nt] = __builtin_amdgcn_mfma_f32_16x16x32_bf16(afh, bl, acc[nt], 0, 0, 0);
                acc[nt] = __builtin_amdgcn_mfma_f32_16x16x32_bf16(afl, bh, acc[nt], 0, 0, 0);
            }
        }
        __syncthreads();
    }

    #pragma unroll
    for (int nt = 0; nt < 4; ++nt) {
        const int n = wc * 64 + nt * 16 + lc;
        #pragma unroll
        for (int r = 0; r < 4; ++r) {
            const int m = m0 + wr * 16 + lr * 4 + r;
            out[(size_t)m * CC + n] = acc[nt][r];
        }
    }
}

extern "C" void kernel_launch(void* const* d_in, const int* in_sizes, int n_in,
                              void* d_out, int out_size, void* d_ws, size_t ws_size,
                              hipStream_t stream) {
    const float* x      = (const float*)d_in[0];
    const float* w_qkv  = (const float*)d_in[1];
    const float* b_qkv  = (const float*)d_in[2];
    const float* rpb    = (const float*)d_in[3];
    const float* w_proj = (const float*)d_in[4];
    const float* b_proj = (const float*)d_in[5];
    float* out = (float*)d_out;

    float* ws  = (float*)d_ws;
    float* qbf = ws;
    float* kbf = ws + QKV_ELE;
    float* vbf = ws + 2 * QKV_ELE;
    float* obf = ws + 3 * QKV_ELE;
    u16* wqT_h = (u16*)(ws + 4 * QKV_ELE);
    u16* wqT_l = wqT_h + 384 * 128;
    u16* wpT_h = wqT_l + 384 * 128;
    u16* wpT_l = wpT_h + 128 * 128;

    prep_w<<<256, 256, 0, stream>>>(w_qkv, w_proj, wqT_h, wqT_l, wpT_h, wpT_l);
    qkv_mfma<<<dim3(196, 3), 256, 0, stream>>>(x, wqT_h, wqT_l, b_qkv, qbf, kbf, vbf);
    natten_attn<<<dim3(49, NHD, BATCH), 256, 0, stream>>>(qbf, kbf, vbf, rpb, obf);
    proj_mfma<<<392, 256, 0, stream>>>(obf, wpT_h, wpT_l, b_proj, out);
}